// Round 7
// baseline (139.204 us; speedup 1.0000x reference)
//
#include <hip/hip_runtime.h>
#include <math.h>

// Problem shapes
// feature: (16, 32, 64, 64) f32
// img:     (16, 3, 512, 512) f32
// conv_w:  (16, 32, 16, 16) f32   (OIHW)
// conv_b:  (16,)
// lin_w:   (25, 144)
// lin_b:   (25,)
// out:     (16, 3, 512, 512) f32

#define B_  16
#define C_  3
#define H_  512
#define W_  512

typedef float nfloat4 __attribute__((ext_vector_type(4)));  // native vec for nontemporal builtins

// ---------------------------------------------------------------------------
// Stage 1: 16x16 conv (pad=1) on the 16x16 feature patch + bias + exact gelu.
// One block per (b, oc); thread <-> spatial tap for all 32 input channels.
// ---------------------------------------------------------------------------
__global__ __launch_bounds__(256) void patch_conv_kernel(
    const float* __restrict__ feature,
    const float* __restrict__ conv_w,
    const float* __restrict__ conv_b,
    float* __restrict__ g_out)
{
    __shared__ float patch_raw[17 + 8192 + 17]; // guard pads for +-17 offsets
    __shared__ float red[9][4];
    float* patch = patch_raw + 17;

    int blk = blockIdx.x;
    int b   = blk >> 4;
    int oc  = blk & 15;
    int tid = threadIdx.x;

    const float* fb = feature + (size_t)b * 32 * 4096;
    const float* wb = conv_w + (size_t)oc * 8192;

    if (tid < 17) { patch_raw[tid] = 0.f; patch_raw[17 + 8192 + tid] = 0.f; }

    for (int i = tid; i < 8192; i += 256) {
        int ic = i >> 8;
        int r  = i & 255;
        patch[i] = fb[ic * 4096 + (r >> 4) * 64 + (r & 15)];
    }

    float wreg[32];
    #pragma unroll
    for (int ic = 0; ic < 32; ic++) wreg[ic] = wb[ic * 256 + tid];

    __syncthreads();

    int kh = tid >> 4;
    int kw = tid & 15;

    float acc[9];
    #pragma unroll
    for (int k = 0; k < 9; k++) acc[k] = 0.f;

    #pragma unroll 4
    for (int ic = 0; ic < 32; ic++) {
        int base = ic * 256 + tid;
        float wv = wreg[ic];
        #pragma unroll
        for (int di = 0; di < 3; di++) {
            #pragma unroll
            for (int dj = 0; dj < 3; dj++) {
                acc[di * 3 + dj] += patch[base + (di - 1) * 16 + (dj - 1)] * wv;
            }
        }
    }

    #pragma unroll
    for (int di = 0; di < 3; di++) {
        #pragma unroll
        for (int dj = 0; dj < 3; dj++) {
            bool ok = ((unsigned)(kh + di - 1) < 16u) &&
                      ((unsigned)(kw + dj - 1) < 16u);
            if (!ok) acc[di * 3 + dj] = 0.f;
        }
    }

    #pragma unroll
    for (int k = 0; k < 9; k++) {
        float v = acc[k];
        #pragma unroll
        for (int off = 32; off > 0; off >>= 1)
            v += __shfl_xor(v, off, 64);
        acc[k] = v;
    }
    int wid  = tid >> 6;
    int lane = tid & 63;
    if (lane == 0) {
        #pragma unroll
        for (int k = 0; k < 9; k++) red[k][wid] = acc[k];
    }
    __syncthreads();
    if (tid < 9) {
        float s = red[tid][0] + red[tid][1] + red[tid][2] + red[tid][3];
        s += conv_b[oc];
        float g = 0.5f * s * (1.0f + erff(s * 0.70710678118654752f));
        g_out[(b * 16 + oc) * 9 + tid] = g;
    }
}

// ---------------------------------------------------------------------------
// Stage 2: kv[b,k] = sum_j g[b,j] * lin_w[k,j] + lin_b[k]
// ---------------------------------------------------------------------------
__global__ __launch_bounds__(256) void kv_kernel(
    const float* __restrict__ g_in,
    const float* __restrict__ lin_w,
    const float* __restrict__ lin_b,
    float* __restrict__ kv_out)
{
    __shared__ float wsh[25 * 144];
    __shared__ float gsh[144];
    int b   = blockIdx.x;
    int tid = threadIdx.x;

    for (int i = tid; i < 25 * 144; i += 256) wsh[i] = lin_w[i];
    if (tid < 144) gsh[tid] = g_in[b * 144 + tid];
    __syncthreads();

    if (tid < 25) {
        float acc = lin_b[tid];
        #pragma unroll 8
        for (int j = 0; j < 144; j++) acc += gsh[j] * wsh[tid * 144 + j];
        kv_out[b * 25 + tid] = acc;
    }
}

// ---------------------------------------------------------------------------
// Stage 3: depthwise 5x5 conv, reflect pad=2. NO LDS, NO barriers.
// FULL-ROW tiles: each block covers the entire 512-wide row band x 16 rows
// (grid 32 x 48). A wave's 64 lanes span 256 contiguous floats of one row ->
// every row load/store is a contiguous 1 KB transaction; the block's input
// window is a sequential 40 KB region (ideal DRAM page/channel locality).
// Per thread: 4 wide x 8 tall, 12-row stream through a 4-row register
// prefetch window. x-reflect touches only lanes at x=0 / x=508 (predicated
// scalar loads). Non-temporal output stores keep L2 for the input halos.
// ---------------------------------------------------------------------------
#define RPB  16          // output rows per block

__device__ __forceinline__ int reflect_idx(int v, int n) {
    v = (v < 0) ? -v : v;
    v = (v >= n) ? (2 * n - 2 - v) : v;
    return v;
}

__global__ __launch_bounds__(256) void depthwise_kernel(
    const float* __restrict__ img,
    const float* __restrict__ kv,
    float* __restrict__ out)
{
    int bc  = blockIdx.y;            // 0..47  (b*3 + c)
    int b   = bc / C_;
    int yb0 = blockIdx.x * RPB;      // first output row of block

    int tid = threadIdx.x;
    int xid = tid & 127;
    int tx  = xid * 4;               // 0..508
    int yg  = tid >> 7;              // 0 or 1
    int ty  = yb0 + yg * 8;          // first output row of thread

    // block-uniform kernel weights -> SGPRs
    float w[25];
    {
        const float* kvp = kv + b * 25;
        #pragma unroll
        for (int i = 0; i < 25; i++)
            w[i] = __int_as_float(
                __builtin_amdgcn_readfirstlane(__float_as_int(kvp[i])));
    }

    const float* ip = img + (size_t)bc * H_ * W_;
    float* op       = out + (size_t)bc * H_ * W_;

    bool edgeL = (tx == 0);
    bool edgeR = (tx == W_ - 4);

    float acc[8][4];
    #pragma unroll
    for (int i = 0; i < 8; i++)
        #pragma unroll
        for (int j = 0; j < 4; j++) acc[i][j] = 0.f;

    float win[4][8];

    // row loader: input row (ty + r - 2), y-reflected; fills dst[0..7]
    #define LOADROW(r, dst)                                              \
    do {                                                                 \
        int gy = reflect_idx(ty + (r) - 2, H_);                          \
        const float* rowp = ip + (size_t)gy * W_;                        \
        const float* rp   = rowp + tx;                                   \
        float2 a, c;                                                     \
        if (edgeL) { a.x = rowp[2];  a.y = rowp[1]; }                    \
        else       { a = *(const float2*)(rp - 2); }                     \
        float4 m = *(const float4*)rp;                                   \
        if (edgeR) { c.x = rowp[W_-2]; c.y = rowp[W_-3]; }               \
        else       { c = *(const float2*)(rp + 4); }                     \
        (dst)[0] = a.x; (dst)[1] = a.y;                                  \
        (dst)[2] = m.x; (dst)[3] = m.y; (dst)[4] = m.z; (dst)[5] = m.w;  \
        (dst)[6] = c.x; (dst)[7] = c.y;                                  \
    } while (0)

    // prefetch rows 0..3
    #pragma unroll
    for (int r = 0; r < 4; r++) {
        LOADROW(r, win[r]);
    }

    // stream 12 rows; consume row r, prefetch row r+4 into the freed slot
    #pragma unroll
    for (int r = 0; r < 12; r++) {
        const float* x = win[r & 3];
        #pragma unroll
        for (int orow = 0; orow < 8; orow++) {
            int dy = r - orow;
            if (dy >= 0 && dy < 5) {            // compile-time after unroll
                #pragma unroll
                for (int dx = 0; dx < 5; dx++) {
                    float wv = w[dy * 5 + dx];
                    #pragma unroll
                    for (int oc = 0; oc < 4; oc++)
                        acc[orow][oc] += wv * x[oc + dx];
                }
            }
        }
        if (r + 4 < 12) {
            float* wdst = win[r & 3];
            LOADROW(r + 4, wdst);
        }
    }
    #undef LOADROW

    #pragma unroll
    for (int orow = 0; orow < 8; orow++) {
        nfloat4 o;
        o.x = acc[orow][0]; o.y = acc[orow][1];
        o.z = acc[orow][2]; o.w = acc[orow][3];
        __builtin_nontemporal_store(
            o, (nfloat4*)&op[(size_t)(ty + orow) * W_ + tx]);
    }
}

extern "C" void kernel_launch(void* const* d_in, const int* in_sizes, int n_in,
                              void* d_out, int out_size, void* d_ws, size_t ws_size,
                              hipStream_t stream) {
    const float* feature = (const float*)d_in[0];
    const float* img     = (const float*)d_in[1];
    const float* conv_w  = (const float*)d_in[2];
    const float* conv_b  = (const float*)d_in[3];
    const float* lin_w   = (const float*)d_in[4];
    const float* lin_b   = (const float*)d_in[5];
    float* out = (float*)d_out;

    float* g_ws  = (float*)d_ws;            // 16*144 floats (post-gelu)
    float* kv_ws = g_ws + 2304;             // 16*25 floats

    patch_conv_kernel<<<B_ * 16, 256, 0, stream>>>(feature, conv_w, conv_b, g_ws);
    kv_kernel<<<B_, 256, 0, stream>>>(g_ws, lin_w, lin_b, kv_ws);

    dim3 grid(H_ / RPB, B_ * C_);   // 32 x 48
    depthwise_kernel<<<grid, 256, 0, stream>>>(img, kv_ws, out);
}